// Round 1
// baseline (110.630 us; speedup 1.0000x reference)
//
#include <hip/hip_runtime.h>
#include <math.h>

// Problem constants (fixed by setup_inputs): B=32, C=256, three channels, N=2048
#define B_SZ   32
#define C_SZ   256
#define N_SZ   2048
#define N4     (N_SZ / 4)            // 512 float4 per (b,c,i) row
#define POS    (C_SZ * N4)           // 131072 float4-positions per batch (c,n) plane
#define ROW3   (3 * N4)              // 1536 float4 per (b,c) block
#define BATCH4 (C_SZ * ROW3)         // 393216 float4 per batch
#define RBLK   64                    // reduce blocks per batch
#define M_D    ((double)(C_SZ) * (double)(N_SZ))   // 524288

// ---------------------------------------------------------------------------
// Kernel 1: per-batch moment reduction.
// For each batch b, accumulate s_i = sum(x_i), q_ij = sum(x_i * x_j) over the
// (c,n) plane. Each block writes 9 fp32 partials; no atomics.
// ---------------------------------------------------------------------------
__global__ __launch_bounds__(256) void vnzca_reduce(const float4* __restrict__ x4,
                                                    float* __restrict__ partials) {
    const int b   = blockIdx.y;
    const int tid = threadIdx.x;
    const int stride = RBLK * 256;

    float s0 = 0.f, s1 = 0.f, s2 = 0.f;
    float q00 = 0.f, q01 = 0.f, q02 = 0.f, q11 = 0.f, q12 = 0.f, q22 = 0.f;

    const float4* xb = x4 + (size_t)b * BATCH4;
    for (int pos = blockIdx.x * 256 + tid; pos < POS; pos += stride) {
        const int c  = pos >> 9;       // / N4
        const int n4 = pos & (N4 - 1);
        const float4* p = xb + c * ROW3 + n4;
        const float4 a = p[0];
        const float4 d = p[N4];
        const float4 e = p[2 * N4];
        s0 += (a.x + a.y) + (a.z + a.w);
        s1 += (d.x + d.y) + (d.z + d.w);
        s2 += (e.x + e.y) + (e.z + e.w);
        q00 += a.x * a.x + a.y * a.y + a.z * a.z + a.w * a.w;
        q01 += a.x * d.x + a.y * d.y + a.z * d.z + a.w * d.w;
        q02 += a.x * e.x + a.y * e.y + a.z * e.z + a.w * e.w;
        q11 += d.x * d.x + d.y * d.y + d.z * d.z + d.w * d.w;
        q12 += d.x * e.x + d.y * e.y + d.z * e.z + d.w * e.w;
        q22 += e.x * e.x + e.y * e.y + e.z * e.z + e.w * e.w;
    }

    float v[9] = {s0, s1, s2, q00, q01, q02, q11, q12, q22};
    __shared__ float red[4][9];
    const int lane = tid & 63, wave = tid >> 6;
    #pragma unroll
    for (int k = 0; k < 9; ++k) {
        float t = v[k];
        #pragma unroll
        for (int o = 32; o > 0; o >>= 1) t += __shfl_down(t, o, 64);
        if (lane == 0) red[wave][k] = t;
    }
    __syncthreads();
    if (tid < 9) {
        partials[((size_t)b * RBLK + blockIdx.x) * 9 + tid] =
            red[0][tid] + red[1][tid] + red[2][tid] + red[3][tid];
    }
}

// ---------------------------------------------------------------------------
// Kernel 2: per-batch 3x3 covariance -> Jacobi eigendecomposition -> W, mu.
// One block (64 threads) per batch; fp64 finish. Writes 12 floats per batch:
// W[0..8] row-major, mu[9..11].
// ---------------------------------------------------------------------------
__global__ __launch_bounds__(64) void vnzca_solve(const float* __restrict__ partials,
                                                  float* __restrict__ wmu) {
    const int b = blockIdx.x;
    const int t = threadIdx.x;

    double v[9];
    #pragma unroll
    for (int k = 0; k < 9; ++k)
        v[k] = (double)partials[((size_t)b * RBLK + t) * 9 + k];
    #pragma unroll
    for (int k = 0; k < 9; ++k) {
        double a = v[k];
        #pragma unroll
        for (int o = 32; o > 0; o >>= 1) a += __shfl_down(a, o, 64);
        v[k] = a;
    }
    if (t != 0) return;

    const double mu0 = v[0] / M_D, mu1 = v[1] / M_D, mu2 = v[2] / M_D;
    const double denom = M_D + 1e-6;

    double A[3][3];
    A[0][0] = (v[3] - M_D * mu0 * mu0) / denom + 1e-5;
    A[0][1] = A[1][0] = (v[4] - M_D * mu0 * mu1) / denom;
    A[0][2] = A[2][0] = (v[5] - M_D * mu0 * mu2) / denom;
    A[1][1] = (v[6] - M_D * mu1 * mu1) / denom + 1e-5;
    A[1][2] = A[2][1] = (v[7] - M_D * mu1 * mu2) / denom;
    A[2][2] = (v[8] - M_D * mu2 * mu2) / denom + 1e-5;

    double V[3][3] = {{1, 0, 0}, {0, 1, 0}, {0, 0, 1}};

    // Cyclic Jacobi, converges cubically; 3x3 symmetric.
    for (int sweep = 0; sweep < 30; ++sweep) {
        const double off = A[0][1] * A[0][1] + A[0][2] * A[0][2] + A[1][2] * A[1][2];
        if (off < 1e-28) break;
        #pragma unroll
        for (int pi = 0; pi < 3; ++pi) {
            const int p = (pi == 0) ? 0 : (pi == 1) ? 0 : 1;
            const int q = (pi == 0) ? 1 : (pi == 1) ? 2 : 2;
            const double apq = A[p][q];
            if (apq == 0.0) continue;
            const double app = A[p][p], aqq = A[q][q];
            const double tau = (aqq - app) / (2.0 * apq);
            const double tt = (tau >= 0.0)
                                  ? 1.0 / (tau + sqrt(1.0 + tau * tau))
                                  : 1.0 / (tau - sqrt(1.0 + tau * tau));
            const double cc = 1.0 / sqrt(1.0 + tt * tt);
            const double ss = tt * cc;
            A[p][p] = app - tt * apq;
            A[q][q] = aqq + tt * apq;
            A[p][q] = A[q][p] = 0.0;
            const int r = 3 - p - q;  // the remaining index
            const double arp = A[r][p], arq = A[r][q];
            A[r][p] = A[p][r] = cc * arp - ss * arq;
            A[r][q] = A[q][r] = ss * arp + cc * arq;
            #pragma unroll
            for (int k = 0; k < 3; ++k) {
                const double vkp = V[k][p], vkq = V[k][q];
                V[k][p] = cc * vkp - ss * vkq;
                V[k][q] = ss * vkp + cc * vkq;
            }
        }
    }

    double w[3];
    #pragma unroll
    for (int i = 0; i < 3; ++i) {
        double lam = A[i][i];
        if (lam < 1e-5) lam = 1e-5;
        w[i] = 1.0 / sqrt(lam);
    }

    float* out = wmu + b * 12;
    #pragma unroll
    for (int i = 0; i < 3; ++i)
        #pragma unroll
        for (int j = 0; j < 3; ++j) {
            const double wij = V[i][0] * w[0] * V[j][0] +
                               V[i][1] * w[1] * V[j][1] +
                               V[i][2] * w[2] * V[j][2];
            out[i * 3 + j] = (float)wij;
        }
    out[9]  = (float)mu0;
    out[10] = (float)mu1;
    out[11] = (float)mu2;
}

// ---------------------------------------------------------------------------
// Kernel 3: y[b,c,i,n] = gamma[c] * sum_j W[i][j] * (x[b,c,j,n] - mu[j])
// ---------------------------------------------------------------------------
__global__ __launch_bounds__(256) void vnzca_apply(const float4* __restrict__ x4,
                                                   const float* __restrict__ gamma,
                                                   const float* __restrict__ wmu,
                                                   float4* __restrict__ y4) {
    const int b   = blockIdx.y;
    const int pos = blockIdx.x * 256 + threadIdx.x;  // [0, POS)

    const float* wb = wmu + b * 12;
    const float W00 = wb[0], W01 = wb[1], W02 = wb[2];
    const float W10 = wb[3], W11 = wb[4], W12 = wb[5];
    const float W20 = wb[6], W21 = wb[7], W22 = wb[8];
    const float mu0 = wb[9], mu1 = wb[10], mu2 = wb[11];

    const int c  = pos >> 9;
    const int n4 = pos & (N4 - 1);
    const size_t base = (size_t)b * BATCH4 + c * ROW3 + n4;

    float4 a = x4[base];
    float4 d = x4[base + N4];
    float4 e = x4[base + 2 * N4];
    const float g = gamma[c];

    a.x -= mu0; a.y -= mu0; a.z -= mu0; a.w -= mu0;
    d.x -= mu1; d.y -= mu1; d.z -= mu1; d.w -= mu1;
    e.x -= mu2; e.y -= mu2; e.z -= mu2; e.w -= mu2;

    float4 y0, y1, y2;
    y0.x = g * (W00 * a.x + W01 * d.x + W02 * e.x);
    y0.y = g * (W00 * a.y + W01 * d.y + W02 * e.y);
    y0.z = g * (W00 * a.z + W01 * d.z + W02 * e.z);
    y0.w = g * (W00 * a.w + W01 * d.w + W02 * e.w);
    y1.x = g * (W10 * a.x + W11 * d.x + W12 * e.x);
    y1.y = g * (W10 * a.y + W11 * d.y + W12 * e.y);
    y1.z = g * (W10 * a.z + W11 * d.z + W12 * e.z);
    y1.w = g * (W10 * a.w + W11 * d.w + W12 * e.w);
    y2.x = g * (W20 * a.x + W21 * d.x + W22 * e.x);
    y2.y = g * (W20 * a.y + W21 * d.y + W22 * e.y);
    y2.z = g * (W20 * a.z + W21 * d.z + W22 * e.z);
    y2.w = g * (W20 * a.w + W21 * d.w + W22 * e.w);

    y4[base]          = y0;
    y4[base + N4]     = y1;
    y4[base + 2 * N4] = y2;
}

extern "C" void kernel_launch(void* const* d_in, const int* in_sizes, int n_in,
                              void* d_out, int out_size, void* d_ws, size_t ws_size,
                              hipStream_t stream) {
    const float4* x4    = (const float4*)d_in[0];
    const float*  gamma = (const float*)d_in[1];
    float*        y4    = (float*)d_out;

    // Workspace layout: partials [B][RBLK][9] fp32, then wmu [B][12] fp32.
    float* partials = (float*)d_ws;                       // 32*64*9 = 18432 floats
    float* wmu      = partials + (size_t)B_SZ * RBLK * 9; // 32*12   =   384 floats

    vnzca_reduce<<<dim3(RBLK, B_SZ), 256, 0, stream>>>(x4, partials);
    vnzca_solve<<<B_SZ, 64, 0, stream>>>(partials, wmu);
    vnzca_apply<<<dim3(POS / 256, B_SZ), 256, 0, stream>>>(x4, gamma, wmu, (float4*)y4);
}

// Round 3
// 101.654 us; speedup vs baseline: 1.0883x; 1.0883x over previous
//
#include <hip/hip_runtime.h>
#include <math.h>

// Problem constants (fixed by setup_inputs): B=32, C=256, three channels, N=2048
#define B_SZ   32
#define C_SZ   256
#define N_SZ   2048
#define N4     (N_SZ / 4)            // 512 float4 per (b,c,i) row
#define POS    (C_SZ * N4)           // 131072 float4-positions per batch (c,n) plane
#define ROW3   (3 * N4)              // 1536 float4 per (b,c) block
#define BATCH4 (C_SZ * ROW3)         // 393216 float4 per batch
#define RBLK   64                    // reduce blocks per batch
#define M_D    ((double)(C_SZ) * (double)(N_SZ))   // 524288

// Native clang vector type — accepted by __builtin_nontemporal_store
// (HIP_vector_type<float,4> is a struct and is rejected).
typedef float nfloat4 __attribute__((ext_vector_type(4)));

// ---------------------------------------------------------------------------
// Kernel 1: per-batch moment reduction.
// For each batch b, accumulate s_i = sum(x_i), q_ij = sum(x_i * x_j) over the
// (c,n) plane. Each block writes 9 fp32 partials; no atomics.
// Loads are CACHING on purpose: they leave x resident in the 256MB L3 so the
// apply pass re-reads it from L3 instead of HBM.
// ---------------------------------------------------------------------------
__global__ __launch_bounds__(256) void vnzca_reduce(const float4* __restrict__ x4,
                                                    float* __restrict__ partials) {
    const int b   = blockIdx.y;
    const int tid = threadIdx.x;
    const int stride = RBLK * 256;

    float s0 = 0.f, s1 = 0.f, s2 = 0.f;
    float q00 = 0.f, q01 = 0.f, q02 = 0.f, q11 = 0.f, q12 = 0.f, q22 = 0.f;

    const float4* xb = x4 + (size_t)b * BATCH4;
    for (int pos = blockIdx.x * 256 + tid; pos < POS; pos += stride) {
        const int c  = pos >> 9;       // / N4
        const int n4 = pos & (N4 - 1);
        const float4* p = xb + c * ROW3 + n4;
        const float4 a = p[0];
        const float4 d = p[N4];
        const float4 e = p[2 * N4];
        s0 += (a.x + a.y) + (a.z + a.w);
        s1 += (d.x + d.y) + (d.z + d.w);
        s2 += (e.x + e.y) + (e.z + e.w);
        q00 += a.x * a.x + a.y * a.y + a.z * a.z + a.w * a.w;
        q01 += a.x * d.x + a.y * d.y + a.z * d.z + a.w * d.w;
        q02 += a.x * e.x + a.y * e.y + a.z * e.z + a.w * e.w;
        q11 += d.x * d.x + d.y * d.y + d.z * d.z + d.w * d.w;
        q12 += d.x * e.x + d.y * e.y + d.z * e.z + d.w * e.w;
        q22 += e.x * e.x + e.y * e.y + e.z * e.z + e.w * e.w;
    }

    float v[9] = {s0, s1, s2, q00, q01, q02, q11, q12, q22};
    __shared__ float red[4][9];
    const int lane = tid & 63, wave = tid >> 6;
    #pragma unroll
    for (int k = 0; k < 9; ++k) {
        float t = v[k];
        #pragma unroll
        for (int o = 32; o > 0; o >>= 1) t += __shfl_down(t, o, 64);
        if (lane == 0) red[wave][k] = t;
    }
    __syncthreads();
    if (tid < 9) {
        partials[((size_t)b * RBLK + blockIdx.x) * 9 + tid] =
            red[0][tid] + red[1][tid] + red[2][tid] + red[3][tid];
    }
}

// ---------------------------------------------------------------------------
// Kernel 2: per-batch 3x3 covariance -> Jacobi eigendecomposition -> W, mu.
// One block (64 threads) per batch; fp64 finish. Writes 12 floats per batch:
// W[0..8] row-major, mu[9..11].
// ---------------------------------------------------------------------------
__global__ __launch_bounds__(64) void vnzca_solve(const float* __restrict__ partials,
                                                  float* __restrict__ wmu) {
    const int b = blockIdx.x;
    const int t = threadIdx.x;

    double v[9];
    #pragma unroll
    for (int k = 0; k < 9; ++k)
        v[k] = (double)partials[((size_t)b * RBLK + t) * 9 + k];
    #pragma unroll
    for (int k = 0; k < 9; ++k) {
        double a = v[k];
        #pragma unroll
        for (int o = 32; o > 0; o >>= 1) a += __shfl_down(a, o, 64);
        v[k] = a;
    }
    if (t != 0) return;

    const double mu0 = v[0] / M_D, mu1 = v[1] / M_D, mu2 = v[2] / M_D;
    const double denom = M_D + 1e-6;

    double A[3][3];
    A[0][0] = (v[3] - M_D * mu0 * mu0) / denom + 1e-5;
    A[0][1] = A[1][0] = (v[4] - M_D * mu0 * mu1) / denom;
    A[0][2] = A[2][0] = (v[5] - M_D * mu0 * mu2) / denom;
    A[1][1] = (v[6] - M_D * mu1 * mu1) / denom + 1e-5;
    A[1][2] = A[2][1] = (v[7] - M_D * mu1 * mu2) / denom;
    A[2][2] = (v[8] - M_D * mu2 * mu2) / denom + 1e-5;

    double V[3][3] = {{1, 0, 0}, {0, 1, 0}, {0, 0, 1}};

    // Cyclic Jacobi, converges cubically; 3x3 symmetric.
    for (int sweep = 0; sweep < 30; ++sweep) {
        const double off = A[0][1] * A[0][1] + A[0][2] * A[0][2] + A[1][2] * A[1][2];
        if (off < 1e-28) break;
        #pragma unroll
        for (int pi = 0; pi < 3; ++pi) {
            const int p = (pi == 0) ? 0 : (pi == 1) ? 0 : 1;
            const int q = (pi == 0) ? 1 : (pi == 1) ? 2 : 2;
            const double apq = A[p][q];
            if (apq == 0.0) continue;
            const double app = A[p][p], aqq = A[q][q];
            const double tau = (aqq - app) / (2.0 * apq);
            const double tt = (tau >= 0.0)
                                  ? 1.0 / (tau + sqrt(1.0 + tau * tau))
                                  : 1.0 / (tau - sqrt(1.0 + tau * tau));
            const double cc = 1.0 / sqrt(1.0 + tt * tt);
            const double ss = tt * cc;
            A[p][p] = app - tt * apq;
            A[q][q] = aqq + tt * apq;
            A[p][q] = A[q][p] = 0.0;
            const int r = 3 - p - q;  // the remaining index
            const double arp = A[r][p], arq = A[r][q];
            A[r][p] = A[p][r] = cc * arp - ss * arq;
            A[r][q] = A[q][r] = ss * arp + cc * arq;
            #pragma unroll
            for (int k = 0; k < 3; ++k) {
                const double vkp = V[k][p], vkq = V[k][q];
                V[k][p] = cc * vkp - ss * vkq;
                V[k][q] = ss * vkp + cc * vkq;
            }
        }
    }

    double w[3];
    #pragma unroll
    for (int i = 0; i < 3; ++i) {
        double lam = A[i][i];
        if (lam < 1e-5) lam = 1e-5;
        w[i] = 1.0 / sqrt(lam);
    }

    float* out = wmu + b * 12;
    #pragma unroll
    for (int i = 0; i < 3; ++i)
        #pragma unroll
        for (int j = 0; j < 3; ++j) {
            const double wij = V[i][0] * w[0] * V[j][0] +
                               V[i][1] * w[1] * V[j][1] +
                               V[i][2] * w[2] * V[j][2];
            out[i * 3 + j] = (float)wij;
        }
    out[9]  = (float)mu0;
    out[10] = (float)mu1;
    out[11] = (float)mu2;
}

// ---------------------------------------------------------------------------
// Kernel 3: y[b,c,i,n] = gamma[c] * sum_j W[i][j] * (x[b,c,j,n] - mu[j])
// x reads come from L3 (left resident by the reduce pass); y stores are
// NONTEMPORAL so they don't evict x from L3 mid-pass.
// ---------------------------------------------------------------------------
__global__ __launch_bounds__(256) void vnzca_apply(const float4* __restrict__ x4,
                                                   const float* __restrict__ gamma,
                                                   const float* __restrict__ wmu,
                                                   float* __restrict__ y) {
    const int b   = blockIdx.y;
    const int pos = blockIdx.x * 256 + threadIdx.x;  // [0, POS)

    const float* wb = wmu + b * 12;
    const float W00 = wb[0], W01 = wb[1], W02 = wb[2];
    const float W10 = wb[3], W11 = wb[4], W12 = wb[5];
    const float W20 = wb[6], W21 = wb[7], W22 = wb[8];
    const float mu0 = wb[9], mu1 = wb[10], mu2 = wb[11];

    const int c  = pos >> 9;
    const int n4 = pos & (N4 - 1);
    const size_t base = (size_t)b * BATCH4 + c * ROW3 + n4;

    float4 a = x4[base];
    float4 d = x4[base + N4];
    float4 e = x4[base + 2 * N4];
    const float g = gamma[c];

    a.x -= mu0; a.y -= mu0; a.z -= mu0; a.w -= mu0;
    d.x -= mu1; d.y -= mu1; d.z -= mu1; d.w -= mu1;
    e.x -= mu2; e.y -= mu2; e.z -= mu2; e.w -= mu2;

    nfloat4 y0, y1, y2;
    y0.x = g * (W00 * a.x + W01 * d.x + W02 * e.x);
    y0.y = g * (W00 * a.y + W01 * d.y + W02 * e.y);
    y0.z = g * (W00 * a.z + W01 * d.z + W02 * e.z);
    y0.w = g * (W00 * a.w + W01 * d.w + W02 * e.w);
    y1.x = g * (W10 * a.x + W11 * d.x + W12 * e.x);
    y1.y = g * (W10 * a.y + W11 * d.y + W12 * e.y);
    y1.z = g * (W10 * a.z + W11 * d.z + W12 * e.z);
    y1.w = g * (W10 * a.w + W11 * d.w + W12 * e.w);
    y2.x = g * (W20 * a.x + W21 * d.x + W22 * e.x);
    y2.y = g * (W20 * a.y + W21 * d.y + W22 * e.y);
    y2.z = g * (W20 * a.z + W21 * d.z + W22 * e.z);
    y2.w = g * (W20 * a.w + W21 * d.w + W22 * e.w);

    nfloat4* yv = (nfloat4*)y;
    __builtin_nontemporal_store(y0, &yv[base]);
    __builtin_nontemporal_store(y1, &yv[base + N4]);
    __builtin_nontemporal_store(y2, &yv[base + 2 * N4]);
}

extern "C" void kernel_launch(void* const* d_in, const int* in_sizes, int n_in,
                              void* d_out, int out_size, void* d_ws, size_t ws_size,
                              hipStream_t stream) {
    const float4* x4    = (const float4*)d_in[0];
    const float*  gamma = (const float*)d_in[1];
    float*        y     = (float*)d_out;

    // Workspace layout: partials [B][RBLK][9] fp32, then wmu [B][12] fp32.
    float* partials = (float*)d_ws;                       // 32*64*9 = 18432 floats
    float* wmu      = partials + (size_t)B_SZ * RBLK * 9; // 32*12   =   384 floats

    vnzca_reduce<<<dim3(RBLK, B_SZ), 256, 0, stream>>>(x4, partials);
    vnzca_solve<<<B_SZ, 64, 0, stream>>>(partials, wmu);
    vnzca_apply<<<dim3(POS / 256, B_SZ), 256, 0, stream>>>(x4, gamma, wmu, y);
}